// Round 1
// baseline (6907.285 us; speedup 1.0000x reference)
//
#include <hip/hip_runtime.h>
#include <hip/hip_bf16.h>

#define NROWS 65536
#define DIM 512
#define DFF 2048
#define LN_EPS 1e-5f

__device__ __forceinline__ float bf2f(unsigned short u) {
  union { unsigned u; float f; } c; c.u = ((unsigned)u) << 16; return c.f;
}
__device__ __forceinline__ unsigned short f2bf(float f) {
  union { float f; unsigned u; } c; c.f = f;
  unsigned r = (c.u + 0x7fffu + ((c.u >> 16) & 1u)) >> 16;
  return (unsigned short)r;
}

// ---------------- row stats: mean + rstd per row of a [N,512] fp32 matrix ----
__launch_bounds__(256)
__global__ void rowstats_k(const float* __restrict__ x, float* __restrict__ rs) {
  int t = threadIdx.x;
  int row = blockIdx.x * 4 + (t >> 6);
  int lane = t & 63;
  const float* p = x + (size_t)row * DIM + lane * 8;
  float4 a = *(const float4*)p;
  float4 b = *(const float4*)(p + 4);
  float s = a.x + a.y + a.z + a.w + b.x + b.y + b.z + b.w;
  float q = a.x*a.x + a.y*a.y + a.z*a.z + a.w*a.w
          + b.x*b.x + b.y*b.y + b.z*b.z + b.w*b.w;
#pragma unroll
  for (int off = 32; off > 0; off >>= 1) {
    s += __shfl_xor(s, off);
    q += __shfl_xor(q, off);
  }
  if (lane == 0) {
    float mean = s * (1.0f / DIM);
    float var = q * (1.0f / DIM) - mean * mean;
    rs[2 * row] = mean;
    rs[2 * row + 1] = rsqrtf(var + LN_EPS);
  }
}

// ---------------- fold LN gamma/beta + linear bias into weights -------------
// Wp[d,j] = g[d]*W[d,j];  c1[j] = sum_d Wp[d,j];  beta[j] = sum_d b[d]*W[d,j] + bias[j]
__launch_bounds__(256)
__global__ void fold_k(const float* __restrict__ W, const float* __restrict__ g,
                       const float* __restrict__ b, const float* __restrict__ bias,
                       float* __restrict__ Wp, float* __restrict__ c1,
                       float* __restrict__ beta, int K, int Nn) {
  int col = blockIdx.x * 256 + threadIdx.x;
  float s1 = 0.f, s2 = 0.f;
  for (int d = 0; d < K; ++d) {
    float w = W[(size_t)d * Nn + col];
    float wp = g[d] * w;
    Wp[(size_t)d * Nn + col] = wp;
    s1 += wp;
    s2 += b[d] * w;
  }
  c1[col] = s1;
  beta[col] = s2 + bias[col];
}

// ---------------- generic 64x64 fp32 GEMM with mode-specific epilogue -------
#define MODE_Q  0   // A=query(f32,LN-folded), out=Q(f32), accumulate sum(Q^2)
#define MODE_WH 1   // A=attn(f32), out = acc + bias + source  (h_pre_ffn)
#define MODE_W1 2   // A=h_pre_ffn(f32,LN-folded), out = gelu(...) as bf16
#define MODE_W2 3   // A=T(bf16), out += acc + bias

template <int MODE>
__launch_bounds__(256)
__global__ void gemm_k(const void* __restrict__ Av, const float* __restrict__ B,
                       void* __restrict__ Ov, int K, int N,
                       const float* __restrict__ rs, const float* __restrict__ c1,
                       const float* __restrict__ beta, const float* __restrict__ addsrc,
                       float* __restrict__ sqq) {
  __shared__ float As[16][68];
  __shared__ float Bs[16][64];
  __shared__ float wr[4];
  const int t = threadIdx.x;
  const int m0 = blockIdx.y * 64;
  const int n0 = blockIdx.x * 64;
  const int tx = t & 15, ty = t >> 4;
  const int arow = t >> 2, ak4 = (t & 3) * 4;
  const int brow = t >> 4, bcol4 = (t & 15) * 4;
  float acc[4][4] = {};

  for (int k0 = 0; k0 < K; k0 += 16) {
    float4 av;
    if constexpr (MODE == MODE_W2) {
      const unsigned short* A = (const unsigned short*)Av;
      ushort4 u = *(const ushort4*)(A + (size_t)(m0 + arow) * K + k0 + ak4);
      av.x = bf2f(u.x); av.y = bf2f(u.y); av.z = bf2f(u.z); av.w = bf2f(u.w);
    } else {
      const float* A = (const float*)Av;
      av = *(const float4*)(A + (size_t)(m0 + arow) * K + k0 + ak4);
    }
    As[ak4 + 0][arow] = av.x;
    As[ak4 + 1][arow] = av.y;
    As[ak4 + 2][arow] = av.z;
    As[ak4 + 3][arow] = av.w;
    *(float4*)&Bs[brow][bcol4] = *(const float4*)(B + (size_t)(k0 + brow) * N + n0 + bcol4);
    __syncthreads();
#pragma unroll
    for (int kk = 0; kk < 16; ++kk) {
      float4 a4 = *(float4*)&As[kk][ty * 4];
      float4 b4 = *(float4*)&Bs[kk][tx * 4];
      float ar[4] = {a4.x, a4.y, a4.z, a4.w};
      float br[4] = {b4.x, b4.y, b4.z, b4.w};
#pragma unroll
      for (int i = 0; i < 4; ++i)
#pragma unroll
        for (int j = 0; j < 4; ++j) acc[i][j] += ar[i] * br[j];
    }
    __syncthreads();
  }

  float lsum = 0.f;
#pragma unroll
  for (int i = 0; i < 4; ++i) {
    const int row = m0 + ty * 4 + i;
    float mean = 0.f, r = 0.f;
    if constexpr (MODE == MODE_Q || MODE == MODE_W1) {
      mean = rs[2 * row];
      r = rs[2 * row + 1];
    }
    float o[4];
#pragma unroll
    for (int j = 0; j < 4; ++j) {
      const int col = n0 + tx * 4 + j;
      float v;
      if constexpr (MODE == MODE_Q || MODE == MODE_W1)
        v = r * acc[i][j] - r * mean * c1[col] + beta[col];
      else
        v = acc[i][j] + beta[col];
      if constexpr (MODE == MODE_Q) lsum += v * v;
      if constexpr (MODE == MODE_W1)
        v = 0.5f * v * (1.0f + erff(v * 0.70710678118654752f));
      o[j] = v;
    }
    if constexpr (MODE == MODE_W1) {
      unsigned short* O = (unsigned short*)Ov;
      ushort4 u;
      u.x = f2bf(o[0]); u.y = f2bf(o[1]); u.z = f2bf(o[2]); u.w = f2bf(o[3]);
      *(ushort4*)(O + (size_t)row * N + n0 + tx * 4) = u;
    } else {
      float* O = (float*)Ov;
      float4 vo;
      vo.x = o[0]; vo.y = o[1]; vo.z = o[2]; vo.w = o[3];
      if constexpr (MODE == MODE_WH) {
        float4 s = *(const float4*)(addsrc + (size_t)row * N + n0 + tx * 4);
        vo.x += s.x; vo.y += s.y; vo.z += s.z; vo.w += s.w;
      }
      if constexpr (MODE == MODE_W2) {
        float4 p = *(const float4*)(O + (size_t)row * N + n0 + tx * 4);
        vo.x += p.x; vo.y += p.y; vo.z += p.z; vo.w += p.w;
      }
      *(float4*)(O + (size_t)row * N + n0 + tx * 4) = vo;
    }
  }
  if constexpr (MODE == MODE_Q) {
#pragma unroll
    for (int off = 32; off > 0; off >>= 1) lsum += __shfl_xor(lsum, off);
    if ((t & 63) == 0) wr[t >> 6] = lsum;
    __syncthreads();
    if (t == 0) atomicAdd(sqq, wr[0] + wr[1] + wr[2] + wr[3]);
  }
}

// ---------------- dual-B GEMM: K and V from source; writes V, reduces K ----
__launch_bounds__(256)
__global__ void gemm_kv_k(const float* __restrict__ A, const float* __restrict__ Bk,
                          const float* __restrict__ Bv, float* __restrict__ V,
                          const float* __restrict__ rs,
                          const float* __restrict__ c1k, const float* __restrict__ betak,
                          const float* __restrict__ c1v, const float* __restrict__ betav,
                          float* __restrict__ S1, float* __restrict__ S2,
                          float* __restrict__ skk) {
  __shared__ float As[16][68];
  __shared__ float Bks[16][64];
  __shared__ float Bvs[16][64];
  __shared__ float sh1[64];
  __shared__ float sh2[64];
  __shared__ float wr[4];
  const int K = DIM, N = DIM;
  const int t = threadIdx.x;
  const int m0 = blockIdx.y * 64;
  const int n0 = blockIdx.x * 64;
  const int tx = t & 15, ty = t >> 4;
  const int arow = t >> 2, ak4 = (t & 3) * 4;
  const int brow = t >> 4, bcol4 = (t & 15) * 4;
  float ack[4][4] = {};
  float acv[4][4] = {};

  for (int k0 = 0; k0 < K; k0 += 16) {
    float4 av = *(const float4*)(A + (size_t)(m0 + arow) * K + k0 + ak4);
    As[ak4 + 0][arow] = av.x;
    As[ak4 + 1][arow] = av.y;
    As[ak4 + 2][arow] = av.z;
    As[ak4 + 3][arow] = av.w;
    *(float4*)&Bks[brow][bcol4] = *(const float4*)(Bk + (size_t)(k0 + brow) * N + n0 + bcol4);
    *(float4*)&Bvs[brow][bcol4] = *(const float4*)(Bv + (size_t)(k0 + brow) * N + n0 + bcol4);
    __syncthreads();
#pragma unroll
    for (int kk = 0; kk < 16; ++kk) {
      float4 a4 = *(float4*)&As[kk][ty * 4];
      float4 bk4 = *(float4*)&Bks[kk][tx * 4];
      float4 bv4 = *(float4*)&Bvs[kk][tx * 4];
      float ar[4] = {a4.x, a4.y, a4.z, a4.w};
      float bkr[4] = {bk4.x, bk4.y, bk4.z, bk4.w};
      float bvr[4] = {bv4.x, bv4.y, bv4.z, bv4.w};
#pragma unroll
      for (int i = 0; i < 4; ++i)
#pragma unroll
        for (int j = 0; j < 4; ++j) {
          ack[i][j] += ar[i] * bkr[j];
          acv[i][j] += ar[i] * bvr[j];
        }
    }
    __syncthreads();
  }

  if (t < 64) { sh1[t] = 0.f; sh2[t] = 0.f; }
  __syncthreads();
  float lskk = 0.f;
#pragma unroll
  for (int i = 0; i < 4; ++i) {
    const int row = m0 + ty * 4 + i;
    float mean = rs[2 * row], r = rs[2 * row + 1];
    float vo[4];
#pragma unroll
    for (int j = 0; j < 4; ++j) {
      const int col = n0 + tx * 4 + j;
      float kv = r * ack[i][j] - r * mean * c1k[col] + betak[col];
      float vv = r * acv[i][j] - r * mean * c1v[col] + betav[col];
      vo[j] = vv;
      lskk += kv * kv;
      atomicAdd(&sh1[tx * 4 + j], kv * vv);
      atomicAdd(&sh2[tx * 4 + j], kv);
    }
    float4 v4;
    v4.x = vo[0]; v4.y = vo[1]; v4.z = vo[2]; v4.w = vo[3];
    *(float4*)(V + (size_t)row * N + n0 + tx * 4) = v4;
  }
#pragma unroll
  for (int off = 32; off > 0; off >>= 1) lskk += __shfl_xor(lskk, off);
  if ((t & 63) == 0) wr[t >> 6] = lskk;
  __syncthreads();
  if (t < 64) {
    atomicAdd(&S1[n0 + t], sh1[t]);
    atomicAdd(&S2[n0 + t], sh2[t]);
  }
  if (t == 0) atomicAdd(skk, wr[0] + wr[1] + wr[2] + wr[3]);
}

// ---------------- elementwise attention, Q updated in place -----------------
__launch_bounds__(256)
__global__ void attn_k(float* __restrict__ Q, const float* __restrict__ V,
                       const float* __restrict__ S1, const float* __restrict__ S2,
                       const float* __restrict__ sqq, const float* __restrict__ skk) {
  int t = threadIdx.x;
  int row = blockIdx.x * 4 + (t >> 6);
  int lane = t & 63;
  int c = lane * 8;
  float inv = rsqrtf(sqq[0] * skk[0]);  // 1/(||Q|| * ||K||)
  const float Nf = (float)NROWS;
  float* qp = Q + (size_t)row * DIM + c;
  const float* vp = V + (size_t)row * DIM + c;
  float4 q0 = *(const float4*)qp, q1 = *(const float4*)(qp + 4);
  float4 v0 = *(const float4*)vp, v1 = *(const float4*)(vp + 4);
  float4 s10 = *(const float4*)(S1 + c), s11 = *(const float4*)(S1 + c + 4);
  float4 s20 = *(const float4*)(S2 + c), s21 = *(const float4*)(S2 + c + 4);
  float part = q0.x * s20.x + q0.y * s20.y + q0.z * s20.z + q0.w * s20.w
             + q1.x * s21.x + q1.y * s21.y + q1.z * s21.z + q1.w * s21.w;
  // 8 lanes per head (64 cols / 8 cols-per-lane); reduce within head group
  part += __shfl_xor(part, 1);
  part += __shfl_xor(part, 2);
  part += __shfl_xor(part, 4);
  float rn = 1.0f / (inv * part + Nf);
  float4 o0, o1;
  o0.x = (q0.x * s10.x * inv + v0.x * Nf) * rn;
  o0.y = (q0.y * s10.y * inv + v0.y * Nf) * rn;
  o0.z = (q0.z * s10.z * inv + v0.z * Nf) * rn;
  o0.w = (q0.w * s10.w * inv + v0.w * Nf) * rn;
  o1.x = (q1.x * s11.x * inv + v1.x * Nf) * rn;
  o1.y = (q1.y * s11.y * inv + v1.y * Nf) * rn;
  o1.z = (q1.z * s11.z * inv + v1.z * Nf) * rn;
  o1.w = (q1.w * s11.w * inv + v1.w * Nf) * rn;
  *(float4*)qp = o0;
  *(float4*)(qp + 4) = o1;
}

extern "C" void kernel_launch(void* const* d_in, const int* in_sizes, int n_in,
                              void* d_out, int out_size, void* d_ws, size_t ws_size,
                              hipStream_t stream) {
  const float* query   = (const float*)d_in[0];
  const float* source  = (const float*)d_in[1];
  const float* Wq      = (const float*)d_in[2];
  const float* bq      = (const float*)d_in[3];
  const float* Wk      = (const float*)d_in[4];
  const float* bk      = (const float*)d_in[5];
  const float* Wv      = (const float*)d_in[6];
  const float* bv      = (const float*)d_in[7];
  const float* Wh      = (const float*)d_in[8];
  const float* bh      = (const float*)d_in[9];
  const float* ln_kv_g = (const float*)d_in[10];
  const float* ln_kv_b = (const float*)d_in[11];
  const float* ln_q_g  = (const float*)d_in[12];
  const float* ln_q_b  = (const float*)d_in[13];
  const float* ln2_g   = (const float*)d_in[14];
  const float* ln2_b   = (const float*)d_in[15];
  const float* W1      = (const float*)d_in[16];
  const float* b1      = (const float*)d_in[17];
  const float* W2      = (const float*)d_in[18];
  const float* b2      = (const float*)d_in[19];
  float* out = (float*)d_out;

  char* w = (char*)d_ws;
  float* Qb = (float*)w;                               // 128 MB
  float* Vb = (float*)(w + (size_t)134217728);         // 128 MB
  unsigned short* Tb = (unsigned short*)w;             // 256 MB, overlays Q+V (both dead)
  float* Wqp = (float*)(w + (size_t)268435456);
  float* Wkp = Wqp + 512 * 512;
  float* Wvp = Wkp + 512 * 512;
  float* W1p = Wvp + 512 * 512;                        // 512*2048
  float* c1q   = W1p + 512 * 2048;
  float* betaq = c1q + 512;
  float* c1k   = betaq + 512;
  float* betak = c1k + 512;
  float* c1v   = betak + 512;
  float* betav = c1v + 512;
  float* c1f   = betav + 512;                          // 2048
  float* betaf = c1f + 2048;                           // 2048
  float* rs_src = betaf + 2048;                        // N*2
  float* rs_qry = rs_src + 2 * NROWS;
  float* rs_h   = rs_qry + 2 * NROWS;
  float* S1  = rs_h + 2 * NROWS;                       // 512
  float* S2  = S1 + 512;                               // 512
  float* SQQ = S2 + 512;
  float* SKK = SQQ + 1;

  hipMemsetAsync(S1, 0, (512 + 512 + 2) * sizeof(float), stream);

  dim3 blk(256);
  rowstats_k<<<NROWS / 4, blk, 0, stream>>>(source, rs_src);
  rowstats_k<<<NROWS / 4, blk, 0, stream>>>(query, rs_qry);
  fold_k<<<2, blk, 0, stream>>>(Wq, ln_q_g, ln_q_b, bq, Wqp, c1q, betaq, 512, 512);
  fold_k<<<2, blk, 0, stream>>>(Wk, ln_kv_g, ln_kv_b, bk, Wkp, c1k, betak, 512, 512);
  fold_k<<<2, blk, 0, stream>>>(Wv, ln_kv_g, ln_kv_b, bv, Wvp, c1v, betav, 512, 512);
  fold_k<<<8, blk, 0, stream>>>(W1, ln2_g, ln2_b, b1, W1p, c1f, betaf, 512, 2048);

  dim3 g512(512 / 64, NROWS / 64);
  gemm_k<MODE_Q><<<g512, blk, 0, stream>>>(query, Wqp, Qb, 512, 512,
                                           rs_qry, c1q, betaq, nullptr, SQQ);
  gemm_kv_k<<<g512, blk, 0, stream>>>(source, Wkp, Wvp, Vb, rs_src,
                                      c1k, betak, c1v, betav, S1, S2, SKK);
  attn_k<<<NROWS / 4, blk, 0, stream>>>(Qb, Vb, S1, S2, SQQ, SKK);
  gemm_k<MODE_WH><<<g512, blk, 0, stream>>>(Qb, Wh, out, 512, 512,
                                            nullptr, nullptr, bh, source, nullptr);
  rowstats_k<<<NROWS / 4, blk, 0, stream>>>(out, rs_h);
  dim3 g2048(2048 / 64, NROWS / 64);
  gemm_k<MODE_W1><<<g2048, blk, 0, stream>>>(out, W1p, Tb, 512, 2048,
                                             rs_h, c1f, betaf, nullptr, nullptr);
  gemm_k<MODE_W2><<<g512, blk, 0, stream>>>(Tb, W2, out, 2048, 512,
                                            nullptr, nullptr, b2, nullptr, nullptr);
}

// Round 2
// 1810.148 us; speedup vs baseline: 3.8159x; 3.8159x over previous
//
#include <hip/hip_runtime.h>
#include <hip/hip_bf16.h>

#define NROWS 65536
#define LN_EPS 1e-5f

typedef __attribute__((ext_vector_type(8))) short bf16x8;
typedef __attribute__((ext_vector_type(4))) float f32x4;

__device__ __forceinline__ float bf2f(unsigned short u) {
  union { unsigned u; float f; } c; c.u = ((unsigned)u) << 16; return c.f;
}
__device__ __forceinline__ unsigned short f2bf(float f) {
  union { float f; unsigned u; } c; c.f = f;
  return (unsigned short)((c.u + 0x7fffu + ((c.u >> 16) & 1u)) >> 16);
}

// ---- row LN stats + normalize + cast to bf16: o[row] = (x[row]-mean)*rstd --
__launch_bounds__(256)
__global__ void normcast_k(const float* __restrict__ x, unsigned short* __restrict__ o) {
  int t = threadIdx.x;
  int row = blockIdx.x * 4 + (t >> 6);
  int lane = t & 63;
  const float* p = x + (size_t)row * 512 + lane * 8;
  float4 a = *(const float4*)p;
  float4 b = *(const float4*)(p + 4);
  float s = a.x + a.y + a.z + a.w + b.x + b.y + b.z + b.w;
  float q = a.x*a.x + a.y*a.y + a.z*a.z + a.w*a.w
          + b.x*b.x + b.y*b.y + b.z*b.z + b.w*b.w;
#pragma unroll
  for (int off = 1; off < 64; off <<= 1) {
    s += __shfl_xor(s, off);
    q += __shfl_xor(q, off);
  }
  float mean = s * (1.0f / 512.0f);
  float r = rsqrtf(q * (1.0f / 512.0f) - mean * mean + LN_EPS);
  float va[8] = {a.x, a.y, a.z, a.w, b.x, b.y, b.z, b.w};
  unsigned pk[4];
#pragma unroll
  for (int i = 0; i < 4; ++i) {
    unsigned lo = f2bf((va[2 * i] - mean) * r);
    unsigned hi = f2bf((va[2 * i + 1] - mean) * r);
    pk[i] = lo | (hi << 16);
  }
  uint4 u; u.x = pk[0]; u.y = pk[1]; u.z = pk[2]; u.w = pk[3];
  *(uint4*)(o + (size_t)row * 512 + lane * 8) = u;
}

// ---- transpose + optional per-K-row scale, fp32 -> bf16:  Wt[n,k]=g[k]*W[k,n]
__launch_bounds__(256)
__global__ void transbf_k(const float* __restrict__ W, const float* __restrict__ g,
                          unsigned short* __restrict__ Wt, int K, int N) {
  __shared__ float tile[32][33];
  int tx = threadIdx.x & 31, ty = threadIdx.x >> 5;
  int n0 = blockIdx.x * 32, k0 = blockIdx.y * 32;
#pragma unroll
  for (int i = 0; i < 4; ++i) {
    int k = k0 + ty + i * 8;
    float gg = g ? g[k] : 1.0f;
    tile[ty + i * 8][tx] = gg * W[(size_t)k * N + n0 + tx];
  }
  __syncthreads();
#pragma unroll
  for (int i = 0; i < 4; ++i) {
    int n = n0 + ty + i * 8;
    Wt[(size_t)n * K + k0 + tx] = f2bf(tile[tx][ty + i * 8]);
  }
}

// ---- beta[n] = sum_k b[k]*W[k,n] + bias[n] --------------------------------
__launch_bounds__(256)
__global__ void betacalc_k(const float* __restrict__ W, const float* __restrict__ b,
                           const float* __restrict__ bias, float* __restrict__ beta,
                           int K, int N) {
  int n = blockIdx.x * 256 + threadIdx.x;
  float s = 0.f;
  for (int k = 0; k < K; ++k) s += b[k] * W[(size_t)k * N + n];
  beta[n] = s + bias[n];
}

// ---- MFMA GEMM: C[M,N] = A[M,K](bf16) @ Bt[N,K](bf16)^T + beta, + epilogue -
#define M_Q  0  // out bf16, reduce sum(v^2) -> scal
#define M_K  1  // out bf16, reduce sum(v^2) -> scal
#define M_V  2  // out fp32
#define M_H  3  // out fp32 = acc + beta + src (residual)
#define M_F1 4  // out bf16 = gelu(acc + beta)
#define M_F2 5  // out fp32 += acc + beta

template <int MODE>
__launch_bounds__(256)
__global__ void mm_k(const unsigned short* __restrict__ A,
                     const unsigned short* __restrict__ Bt,
                     void* __restrict__ Ov,
                     const float* __restrict__ beta,
                     const float* __restrict__ src,
                     float* __restrict__ scal,
                     int N, int K) {
  __shared__ __align__(16) unsigned short As[128 * 64];
  __shared__ __align__(16) unsigned short Bs[128 * 64];
  __shared__ float red[4];
  const int t = threadIdx.x;
  const int lane = t & 63;
  const int wave = t >> 6;
  const int m0 = blockIdx.y * 128;
  const int n0 = blockIdx.x * 128;

  const int srow = lane >> 3;                   // 0..7: row within 8-row chunk
  const int sxor = ((lane & 7) ^ srow) * 8;     // swizzled k-offset (elements)
  const int wm = (wave >> 1) * 64;
  const int wn = (wave & 1) * 64;
  const int quad = lane >> 4;
  const int l15 = lane & 15;
  const int l7 = lane & 7;

  f32x4 acc[4][4];
#pragma unroll
  for (int i = 0; i < 4; ++i)
#pragma unroll
    for (int j = 0; j < 4; ++j) acc[i][j] = (f32x4){0.f, 0.f, 0.f, 0.f};

  for (int k0 = 0; k0 < K; k0 += 64) {
    __syncthreads();
#pragma unroll
    for (int i = 0; i < 4; ++i) {
      int c = wave * 4 + i;
      int grow = c * 8 + srow;
      const unsigned short* ga = A + (size_t)(m0 + grow) * K + k0 + sxor;
      const unsigned short* gb = Bt + (size_t)(n0 + grow) * K + k0 + sxor;
      __builtin_amdgcn_global_load_lds(
          (const __attribute__((address_space(1))) void*)ga,
          (__attribute__((address_space(3))) void*)(As + c * 512), 16, 0, 0);
      __builtin_amdgcn_global_load_lds(
          (const __attribute__((address_space(1))) void*)gb,
          (__attribute__((address_space(3))) void*)(Bs + c * 512), 16, 0, 0);
    }
    __syncthreads();
#pragma unroll
    for (int kt = 0; kt < 2; ++kt) {
      const int pb = ((kt * 4 + quad) ^ l7) * 8;
      bf16x8 af[4], bfr[4];
#pragma unroll
      for (int x = 0; x < 4; ++x) {
        af[x]  = *(const bf16x8*)(As + (wm + x * 16 + l15) * 64 + pb);
        bfr[x] = *(const bf16x8*)(Bs + (wn + x * 16 + l15) * 64 + pb);
      }
#pragma unroll
      for (int mi = 0; mi < 4; ++mi)
#pragma unroll
        for (int nj = 0; nj < 4; ++nj)
          acc[mi][nj] = __builtin_amdgcn_mfma_f32_16x16x32_bf16(
              af[mi], bfr[nj], acc[mi][nj], 0, 0, 0);
    }
  }

  float lred = 0.f;
#pragma unroll
  for (int mi = 0; mi < 4; ++mi) {
#pragma unroll
    for (int nj = 0; nj < 4; ++nj) {
      const int col = n0 + wn + nj * 16 + l15;
      const float bet = beta[col];
#pragma unroll
      for (int r = 0; r < 4; ++r) {
        const int row = m0 + wm + mi * 16 + quad * 4 + r;
        const size_t idx = (size_t)row * N + col;
        float v = acc[mi][nj][r] + bet;
        if constexpr (MODE == M_Q || MODE == M_K) {
          lred += v * v;
          ((unsigned short*)Ov)[idx] = f2bf(v);
        } else if constexpr (MODE == M_V) {
          ((float*)Ov)[idx] = v;
        } else if constexpr (MODE == M_H) {
          ((float*)Ov)[idx] = v + src[idx];
        } else if constexpr (MODE == M_F1) {
          float gl = 0.5f * v * (1.0f + erff(v * 0.70710678118654752f));
          ((unsigned short*)Ov)[idx] = f2bf(gl);
        } else {
          ((float*)Ov)[idx] += v;
        }
      }
    }
  }
  if constexpr (MODE == M_Q || MODE == M_K) {
#pragma unroll
    for (int off = 32; off > 0; off >>= 1) lred += __shfl_xor(lred, off);
    if (lane == 0) red[wave] = lred;
    __syncthreads();
    if (t == 0) atomicAdd(scal, red[0] + red[1] + red[2] + red[3]);
  }
}

// ---- column reduction: S1[c]=sum_n K*V, S2[c]=sum_n K ----------------------
__launch_bounds__(256)
__global__ void colred_k(const unsigned short* __restrict__ Kb,
                         const float* __restrict__ Vb,
                         float* __restrict__ S1, float* __restrict__ S2) {
  int t = threadIdx.x;
  int c0 = t * 2;
  int r0 = blockIdx.x * 256;
  float s1a = 0.f, s1b = 0.f, s2a = 0.f, s2b = 0.f;
  for (int r = 0; r < 256; ++r) {
    unsigned u = *(const unsigned*)(Kb + (size_t)(r0 + r) * 512 + c0);
    float k0 = bf2f((unsigned short)(u & 0xffff));
    float k1 = bf2f((unsigned short)(u >> 16));
    float2 v = *(const float2*)(Vb + (size_t)(r0 + r) * 512 + c0);
    s1a += k0 * v.x; s1b += k1 * v.y;
    s2a += k0;       s2b += k1;
  }
  atomicAdd(&S1[c0], s1a); atomicAdd(&S1[c0 + 1], s1b);
  atomicAdd(&S2[c0], s2a); atomicAdd(&S2[c0 + 1], s2b);
}

// ---- elementwise attention; reads Q bf16, writes attn bf16 in place --------
__launch_bounds__(256)
__global__ void attn_k(unsigned short* __restrict__ Qb, const float* __restrict__ Vb,
                       const float* __restrict__ S1, const float* __restrict__ S2,
                       const float* __restrict__ sqq, const float* __restrict__ skk) {
  int t = threadIdx.x;
  int row = blockIdx.x * 4 + (t >> 6);
  int lane = t & 63;
  int c = lane * 8;
  float inv = rsqrtf(sqq[0] * skk[0]);
  const float Nf = (float)NROWS;
  unsigned short* qp = Qb + (size_t)row * 512 + c;
  uint4 qu = *(const uint4*)qp;
  float q[8];
  q[0] = bf2f((unsigned short)(qu.x & 0xffff)); q[1] = bf2f((unsigned short)(qu.x >> 16));
  q[2] = bf2f((unsigned short)(qu.y & 0xffff)); q[3] = bf2f((unsigned short)(qu.y >> 16));
  q[4] = bf2f((unsigned short)(qu.z & 0xffff)); q[5] = bf2f((unsigned short)(qu.z >> 16));
  q[6] = bf2f((unsigned short)(qu.w & 0xffff)); q[7] = bf2f((unsigned short)(qu.w >> 16));
  const float* vp = Vb + (size_t)row * 512 + c;
  float4 v0 = *(const float4*)vp, v1 = *(const float4*)(vp + 4);
  float vv[8] = {v0.x, v0.y, v0.z, v0.w, v1.x, v1.y, v1.z, v1.w};
  float4 s10 = *(const float4*)(S1 + c), s11 = *(const float4*)(S1 + c + 4);
  float4 s20 = *(const float4*)(S2 + c), s21 = *(const float4*)(S2 + c + 4);
  float s1v[8] = {s10.x, s10.y, s10.z, s10.w, s11.x, s11.y, s11.z, s11.w};
  float s2v[8] = {s20.x, s20.y, s20.z, s20.w, s21.x, s21.y, s21.z, s21.w};
  float part = 0.f;
#pragma unroll
  for (int i = 0; i < 8; ++i) part += q[i] * s2v[i];
  part += __shfl_xor(part, 1);
  part += __shfl_xor(part, 2);
  part += __shfl_xor(part, 4);
  float rn = 1.0f / (inv * part + Nf);
  unsigned pk[4];
#pragma unroll
  for (int i = 0; i < 4; ++i) {
    float o0 = (q[2 * i] * s1v[2 * i] * inv + vv[2 * i] * Nf) * rn;
    float o1 = (q[2 * i + 1] * s1v[2 * i + 1] * inv + vv[2 * i + 1] * Nf) * rn;
    pk[i] = (unsigned)f2bf(o0) | ((unsigned)f2bf(o1) << 16);
  }
  uint4 u; u.x = pk[0]; u.y = pk[1]; u.z = pk[2]; u.w = pk[3];
  *(uint4*)qp = u;
}

extern "C" void kernel_launch(void* const* d_in, const int* in_sizes, int n_in,
                              void* d_out, int out_size, void* d_ws, size_t ws_size,
                              hipStream_t stream) {
  const float* query   = (const float*)d_in[0];
  const float* source  = (const float*)d_in[1];
  const float* Wq      = (const float*)d_in[2];
  const float* bq      = (const float*)d_in[3];
  const float* Wk      = (const float*)d_in[4];
  const float* bk      = (const float*)d_in[5];
  const float* Wv      = (const float*)d_in[6];
  const float* bv      = (const float*)d_in[7];
  const float* Wh      = (const float*)d_in[8];
  const float* bh      = (const float*)d_in[9];
  const float* ln_kv_g = (const float*)d_in[10];
  const float* ln_kv_b = (const float*)d_in[11];
  const float* ln_q_g  = (const float*)d_in[12];
  const float* ln_q_b  = (const float*)d_in[13];
  const float* ln2_g   = (const float*)d_in[14];
  const float* ln2_b   = (const float*)d_in[15];
  const float* W1      = (const float*)d_in[16];
  const float* b1      = (const float*)d_in[17];
  const float* W2      = (const float*)d_in[18];
  const float* b2      = (const float*)d_in[19];
  float* out = (float*)d_out;

  const size_t MB = 1024 * 1024;
  char* w = (char*)d_ws;
  unsigned short* Qn = (unsigned short*)(w + 0 * MB);    // 64 MB bf16 normalized query
  unsigned short* Sn = (unsigned short*)(w + 64 * MB);   // 64 MB bf16 normalized source
  unsigned short* Qb = (unsigned short*)(w + 128 * MB);  // 64 MB bf16 Q (then attn, in place)
  unsigned short* Kb = (unsigned short*)(w + 192 * MB);  // 64 MB bf16 K
  float*          Vb = (float*)(w + 256 * MB);           // 128 MB fp32 V
  unsigned short* Hn = (unsigned short*)(w + 256 * MB);  // 64 MB bf16 LN(h)  (after Vb dead)
  unsigned short* Tb = (unsigned short*)(w + 0 * MB);    // 256 MB bf16 gelu out (overlays)
  char* wt = w + 384 * MB;
  unsigned short* Wqt = (unsigned short*)wt;             // 512 KB each
  unsigned short* Wkt = Wqt + 512 * 512;
  unsigned short* Wvt = Wkt + 512 * 512;
  unsigned short* Wht = Wvt + 512 * 512;
  unsigned short* W1t = Wht + 512 * 512;                 // 2 MB
  unsigned short* W2t = W1t + 512 * 2048;                // 2 MB
  float* betaq = (float*)(W2t + 2048 * 512);
  float* betak = betaq + 512;
  float* betav = betak + 512;
  float* betaf = betav + 512;                            // 2048
  float* S1 = betaf + 2048;                              // 512
  float* S2 = S1 + 512;                                  // 512
  float* SQQ = S2 + 512;
  float* SKK = SQQ + 1;

  hipMemsetAsync(S1, 0, (512 + 512 + 2) * sizeof(float), stream);

  dim3 blk(256);
  normcast_k<<<NROWS / 4, blk, 0, stream>>>(query, Qn);
  normcast_k<<<NROWS / 4, blk, 0, stream>>>(source, Sn);
  transbf_k<<<dim3(16, 16), blk, 0, stream>>>(Wq, ln_q_g, Wqt, 512, 512);
  transbf_k<<<dim3(16, 16), blk, 0, stream>>>(Wk, ln_kv_g, Wkt, 512, 512);
  transbf_k<<<dim3(16, 16), blk, 0, stream>>>(Wv, ln_kv_g, Wvt, 512, 512);
  transbf_k<<<dim3(16, 16), blk, 0, stream>>>(Wh, nullptr, Wht, 512, 512);
  transbf_k<<<dim3(64, 16), blk, 0, stream>>>(W1, ln2_g, W1t, 512, 2048);
  transbf_k<<<dim3(16, 64), blk, 0, stream>>>(W2, nullptr, W2t, 2048, 512);
  betacalc_k<<<2, blk, 0, stream>>>(Wq, ln_q_b, bq, betaq, 512, 512);
  betacalc_k<<<2, blk, 0, stream>>>(Wk, ln_kv_b, bk, betak, 512, 512);
  betacalc_k<<<2, blk, 0, stream>>>(Wv, ln_kv_b, bv, betav, 512, 512);
  betacalc_k<<<8, blk, 0, stream>>>(W1, ln2_b, b1, betaf, 512, 2048);

  dim3 g512(4, 512);
  mm_k<M_Q><<<g512, blk, 0, stream>>>(Qn, Wqt, Qb, betaq, nullptr, SQQ, 512, 512);
  mm_k<M_K><<<g512, blk, 0, stream>>>(Sn, Wkt, Kb, betak, nullptr, SKK, 512, 512);
  mm_k<M_V><<<g512, blk, 0, stream>>>(Sn, Wvt, Vb, betav, nullptr, nullptr, 512, 512);
  colred_k<<<NROWS / 256, blk, 0, stream>>>(Kb, Vb, S1, S2);
  attn_k<<<NROWS / 4, blk, 0, stream>>>(Qb, Vb, S1, S2, SQQ, SKK);
  mm_k<M_H><<<g512, blk, 0, stream>>>(Qb, Wht, out, bh, source, nullptr, 512, 512);
  normcast_k<<<NROWS / 4, blk, 0, stream>>>(out, Hn);
  dim3 g2048(16, 512);
  mm_k<M_F1><<<g2048, blk, 0, stream>>>(Hn, W1t, Tb, betaf, nullptr, nullptr, 2048, 512);
  mm_k<M_F2><<<g512, blk, 0, stream>>>(Tb, W2t, out, b2, nullptr, nullptr, 512, 2048);
}